// Round 9
// baseline (203.629 us; speedup 1.0000x reference)
//
#include <hip/hip_runtime.h>

typedef unsigned short u16;
typedef unsigned int   u32;
typedef __bf16 bf16x8 __attribute__((ext_vector_type(8)));
typedef float  f32x4  __attribute__((ext_vector_type(4)));

#define D_MODEL 1024
#define SEQ     2048
#define NHEAD   16
#define HD      64
// (1/sqrt(64)) * log2(e): folded into Q at the projection epilogue
#define SOFTMAX_SCL 0.18033688011112042f

__device__ __forceinline__ u16 f2bf(float f) {
    u32 u;
    __builtin_memcpy(&u, &f, 4);
    u32 r = (u + 0x7fffu + ((u >> 16) & 1u)) >> 16;
    return (u16)r;
}
__device__ __forceinline__ float bf2f(u16 v) {
    u32 u = ((u32)v) << 16;
    float f;
    __builtin_memcpy(&f, &u, 4);
    return f;
}
__device__ __forceinline__ u32 fbits(float f) {
    u32 u;
    __builtin_memcpy(&u, &f, 4);
    return u;
}

__device__ __forceinline__ void async_copy16(const u16* g, u16* l) {
    __builtin_amdgcn_global_load_lds(
        (__attribute__((address_space(1))) void*)g,
        (__attribute__((address_space(3))) void*)l, 16, 0, 0);
}

// ---------------------------------------------------------------------------
// fused fp32 -> bf16 conversion for x, wq, wk, wv (one launch)
// ---------------------------------------------------------------------------
#define NX4 ((2 * SEQ * D_MODEL) / 4)     // 1,048,576
#define NW4 ((D_MODEL * D_MODEL) / 4)     //   262,144
__global__ __launch_bounds__(256) void conv_all(
    const float* __restrict__ x,  const float* __restrict__ wq,
    const float* __restrict__ wk, const float* __restrict__ wv,
    u16* __restrict__ xb, u16* __restrict__ wqb,
    u16* __restrict__ wkb, u16* __restrict__ wvb)
{
    int i = blockIdx.x * 256 + threadIdx.x;
    const float* src; u16* dst; int off;
    if (i < NX4)            { src = x;  dst = xb;  off = i; }
    else if (i < NX4 + NW4) { src = wq; dst = wqb; off = i - NX4; }
    else if (i < NX4 + 2 * NW4) { src = wk; dst = wkb; off = i - NX4 - NW4; }
    else                    { src = wv; dst = wvb; off = i - NX4 - 2 * NW4; }
    float4 a = ((const float4*)src)[off];
    ushort4 o;
    o.x = f2bf(a.x); o.y = f2bf(a.y); o.z = f2bf(a.z); o.w = f2bf(a.w);
    ((ushort4*)dst)[off] = o;
}

// ---------------------------------------------------------------------------
// QKV projection, 128x128 tile, BK=64, global_load_lds, XOR-swizzled LDS.
// 1-D XCD-pinned grid: bid = (z*8+x) + 24*y  ->  bid%8 constant across y.
// ---------------------------------------------------------------------------
__global__ __launch_bounds__(256) void qkv_gemm(
    const u16* __restrict__ xb,
    const u16* __restrict__ wqb, const float* __restrict__ bq,
    const u16* __restrict__ wkb, const float* __restrict__ bk,
    const u16* __restrict__ wvb, const float* __restrict__ bv,
    u16* __restrict__ qb, u16* __restrict__ kb, u16* __restrict__ vt)
{
    const int bid  = blockIdx.x;
    const int pair = bid % 24;
    const int by   = bid / 24;
    const int z    = pair >> 3;
    const int bx   = pair & 7;

    const u16* Ap; const u16* Bp;
    int m0, n0;
    if (z < 2) {
        Ap = xb; Bp = (z == 1) ? wkb : wqb;
        m0 = by * 128;
        n0 = bx * 128;
    } else {
        Ap = wvb; Bp = xb;
        m0 = bx * 128;
        n0 = by * 128;
    }

    __shared__ u16 As[128 * 64];
    __shared__ u16 Bs[128 * 64];

    const int tid  = threadIdx.x;
    const int wave = tid >> 6;
    const int lane = tid & 63;
    const int quad = lane >> 4;
    const int l16  = lane & 15;
    const int wm   = wave >> 1;
    const int wn   = wave & 1;
    const int swz  = l16 & 7;

    int rr[4], co[4];
#pragma unroll
    for (int t = 0; t < 4; ++t) {
        int ch = (wave * 4 + t) * 64 + lane;
        rr[t] = ch >> 3;
        co[t] = ((ch & 7) ^ (rr[t] & 7)) * 8;
    }

    f32x4 acc[4][4] = {};

    for (int kt = 0; kt < D_MODEL; kt += 64) {
        __syncthreads();
#pragma unroll
        for (int t = 0; t < 4; ++t) {
            int chbase = (wave * 4 + t) * 64;
            async_copy16(Ap + (size_t)(m0 + rr[t]) * D_MODEL + kt + co[t], As + chbase * 8);
            async_copy16(Bp + (size_t)(n0 + rr[t]) * D_MODEL + kt + co[t], Bs + chbase * 8);
        }
        __syncthreads();

#pragma unroll
        for (int kc = 0; kc < 2; ++kc) {
            bf16x8 af[4], bf_[4];
#pragma unroll
            for (int i = 0; i < 4; ++i)
                af[i] = *(const bf16x8*)&As[(wm * 64 + i * 16 + l16) * 64 + (((kc * 4 + quad) ^ swz) << 3)];
#pragma unroll
            for (int j = 0; j < 4; ++j)
                bf_[j] = *(const bf16x8*)&Bs[(wn * 64 + j * 16 + l16) * 64 + (((kc * 4 + quad) ^ swz) << 3)];
#pragma unroll
            for (int i = 0; i < 4; ++i)
#pragma unroll
                for (int j = 0; j < 4; ++j)
                    acc[i][j] = __builtin_amdgcn_mfma_f32_16x16x32_bf16(af[i], bf_[j], acc[i][j], 0, 0, 0);
        }
    }

    if (z < 2) {
        u16* out = (z == 1) ? kb : qb;
        const float* bi = (z == 1) ? bk : bq;
        const float scl = (z == 1) ? 1.0f : SOFTMAX_SCL;
#pragma unroll
        for (int j = 0; j < 4; ++j) {
            int col = n0 + wn * 64 + j * 16 + l16;
            float bias = bi[col];
            int colbase = col & ~63;
            int dc  = (col >> 3) & 7;
            int dlo = col & 7;
#pragma unroll
            for (int i = 0; i < 4; ++i) {
#pragma unroll
                for (int r = 0; r < 4; ++r) {
                    int row = m0 + wm * 64 + i * 16 + quad * 4 + r;
                    size_t addr = (size_t)row * D_MODEL + colbase + ((dc ^ (row & 7)) << 3) + dlo;
                    out[addr] = f2bf((acc[i][j][r] + bias) * scl);
                }
            }
        }
    } else {
#pragma unroll
        for (int i = 0; i < 4; ++i) {
#pragma unroll
            for (int r = 0; r < 4; ++r) {
                int feat = m0 + wm * 64 + i * 16 + quad * 4 + r;
                float bias = bv[feat];
                int h = feat >> 6, d = feat & 63;
#pragma unroll
                for (int j = 0; j < 4; ++j) {
                    int tok = n0 + wn * 64 + j * 16 + l16;
                    int b = tok >> 11, s = tok & 2047;
                    size_t addr = ((size_t)(b * NHEAD + h) * HD + d) * SEQ
                                + (s & ~63) + (((((s >> 3) & 7) ^ (d & 7)) << 3)) + (s & 7);
                    vt[addr] = f2bf(acc[i][j][r] + bias);
                }
            }
        }
    }
}

// ---------------------------------------------------------------------------
// Attention with TRANSPOSED score computation (S^T = K.Q^T): each thread's
// 16 S-values belong to ONE q-row (q = l16) as 4 key-pairs x 4 key-blocks.
// -> P pack = v_perm pairs, Ps writes = 4x ds_write_b64/rb, lsum = 1 scalar.
// Block-level 2-way key split retained: writes unnormalized O + row sums.
// ---------------------------------------------------------------------------
__global__ __launch_bounds__(256) void attn_kernel(
    const u16* __restrict__ qb, const u16* __restrict__ kb, const u16* __restrict__ vtg,
    u16* __restrict__ abp, float* __restrict__ lsums)
{
    const int bid  = blockIdx.x;
    const int bh   = bid & 31;
    const int b    = bh >> 4;
    const int h    = bh & 15;
    const int q0   = ((bid >> 5) & 15) * 128;
    const int half = bid >> 9;

    const int tid  = threadIdx.x;
    const int wave = tid >> 6;
    const int lane = tid & 63;
    const int quad = lane >> 4;
    const int l16  = lane & 15;
    const int swz  = l16 & 7;
    const int pswz = swz * 8;          // Ps key swizzle (8-key granularity)

    __shared__ u16 Ks[4096];           // [token][chunk^(token&7)][8]
    __shared__ u16 Vt[4096];           // [d][chunk^(d&7)][8]
    __shared__ u16 Ps[4096];           // [wave][q=16][key'=64] (per-rb reuse)

    const size_t kbase = (size_t)b * SEQ * D_MODEL + h * 64;
    const size_t vbase = (size_t)(b * NHEAD + h) * HD * SEQ;

    // Q fragments (B-operand): 2 row groups x 2 d-chunks
    bf16x8 aq[2][2];
#pragma unroll
    for (int rb = 0; rb < 2; ++rb) {
        const int qrow = q0 + wave * 32 + rb * 16 + l16;
        const u16* qrp = qb + (size_t)qrow * D_MODEL + h * 64;
        aq[rb][0] = *(const bf16x8*)(qrp + ((quad ^ swz) << 3));
        aq[rb][1] = *(const bf16x8*)(qrp + (((4 + quad) ^ swz) << 3));
    }

    // staging pointers (offset into this block's 1024-key half)
    const int r0 = tid >> 3, r1 = (tid + 256) >> 3;
    const int cs8 = (tid & 7) * 8;
    const u16* kg0 = kb + kbase + (size_t)(half * 1024 + r0) * D_MODEL + cs8;
    const u16* kg1 = kb + kbase + (size_t)(half * 1024 + r1) * D_MODEL + cs8;
    const u16* vg0 = vtg + vbase + (size_t)r0 * SEQ + half * 1024 + cs8;
    const u16* vg1 = vtg + vbase + (size_t)r1 * SEQ + half * 1024 + cs8;
    const int wofs = wave * 512;

    f32x4 oacc[2][4] = {};
    float lsum[2] = {0.f, 0.f};

    for (int t = 0; t < 16; ++t) {
        __syncthreads();   // previous tile fully consumed
        async_copy16(kg0, Ks + wofs);
        async_copy16(kg1, Ks + 2048 + wofs);
        async_copy16(vg0, Vt + wofs);
        async_copy16(vg1, Vt + 2048 + wofs);
        kg0 += 64 * D_MODEL; kg1 += 64 * D_MODEL;
        vg0 += 64;           vg1 += 64;
        __syncthreads();   // staging complete (vmcnt drained at barrier)

        // K fragments, A-layout: m=key (kb2*16+l16), k=d (c*32+quad*8)
        bf16x8 kf[4][2];
#pragma unroll
        for (int kb2 = 0; kb2 < 4; ++kb2)
#pragma unroll
            for (int c = 0; c < 2; ++c)
                kf[kb2][c] = *(const bf16x8*)&Ks[(kb2 * 16 + l16) * 64 + (((c * 4 + quad) ^ swz) << 3)];

#pragma unroll
        for (int rb = 0; rb < 2; ++rb) {
            // S^T = K.Q^T : D[key][q]; thread holds q=l16, keys kb2*16+quad*4+r
            f32x4 sacc[4] = {};
#pragma unroll
            for (int kb2 = 0; kb2 < 4; ++kb2) {
                sacc[kb2] = __builtin_amdgcn_mfma_f32_16x16x32_bf16(kf[kb2][0], aq[rb][0], sacc[kb2], 0, 0, 0);
                sacc[kb2] = __builtin_amdgcn_mfma_f32_16x16x32_bf16(kf[kb2][1], aq[rb][1], sacc[kb2], 0, 0, 0);
            }

            // p = 2^S; pair-pack via v_perm; 1 ds_write_b64 per key-block
#pragma unroll
            for (int kb2 = 0; kb2 < 4; ++kb2) {
                float e0 = exp2f(sacc[kb2][0]);
                float e1 = exp2f(sacc[kb2][1]);
                float e2 = exp2f(sacc[kb2][2]);
                float e3 = exp2f(sacc[kb2][3]);
                lsum[rb] += (e0 + e1) + (e2 + e3);
                u32 p0 = __builtin_amdgcn_perm(fbits(e1), fbits(e0), 0x07060302u);
                u32 p1 = __builtin_amdgcn_perm(fbits(e3), fbits(e2), 0x07060302u);
                int k0 = (kb2 * 16 + quad * 4) ^ pswz;
                uint2 pk; pk.x = p0; pk.y = p1;
                *(uint2*)&Ps[wave * 1024 + l16 * 64 + k0] = pk;
            }

            // O += P.V  (A from Ps: 8 consecutive swizzled keys; wave-local
            // DS ordering covers write->read and the rb0->rb1 slot reuse)
#pragma unroll
            for (int c = 0; c < 2; ++c) {
                bf16x8 ap = *(const bf16x8*)&Ps[wave * 1024 + l16 * 64 + ((c * 32 + quad * 8) ^ pswz)];
#pragma unroll
                for (int nb = 0; nb < 4; ++nb) {
                    bf16x8 vf = *(const bf16x8*)&Vt[(nb * 16 + l16) * 64 + (((c * 4 + quad) ^ swz) << 3)];
                    oacc[rb][nb] = __builtin_amdgcn_mfma_f32_16x16x32_bf16(ap, vf, oacc[rb][nb], 0, 0, 0);
                }
            }
        }
    }

    // epilogue: reduce lsum over quads (2 shuffles), store sums + raw O
#pragma unroll
    for (int rb = 0; rb < 2; ++rb) {
        float s = lsum[rb];
        s += __shfl_xor(s, 16, 64);
        s += __shfl_xor(s, 32, 64);
        int qrow = q0 + wave * 32 + rb * 16 + l16;
        if (quad == 0)
            lsums[((size_t)bh * 2 + half) * SEQ + qrow] = s;
#pragma unroll
        for (int r = 0; r < 4; ++r) {
            int row = q0 + wave * 32 + rb * 16 + quad * 4 + r;
#pragma unroll
            for (int nb = 0; nb < 4; ++nb) {
                int d = nb * 16 + l16;
                abp[(size_t)half * SEQ * 2 * D_MODEL
                    + ((size_t)b * SEQ + row) * D_MODEL + h * 64 + d] = f2bf(oacc[rb][nb][r]);
            }
        }
    }
}

// ---------------------------------------------------------------------------
// combine key-halves + residual add + LayerNorm, one block per row of 1024
// ---------------------------------------------------------------------------
__global__ __launch_bounds__(256) void add_ln(
    const u16* __restrict__ abp, const float* __restrict__ lsums,
    const float* __restrict__ x,
    const float* __restrict__ gamma, const float* __restrict__ beta,
    float* __restrict__ out)
{
    const int row = blockIdx.x;           // (b, s)
    const int tid = threadIdx.x;
    const size_t rb = (size_t)row * D_MODEL;
    const int b = row >> 11, s = row & 2047;
    const int h = tid >> 4;               // head of this thread's 4 columns
    const int bh = b * NHEAD + h;

    float l = lsums[(size_t)bh * 2 * SEQ + s] + lsums[((size_t)bh * 2 + 1) * SEQ + s];
    float inv = 1.0f / l;

    uint2 a0 = ((const uint2*)(abp + rb))[tid];
    uint2 a1 = ((const uint2*)(abp + (size_t)SEQ * 2 * D_MODEL + rb))[tid];
    float4 xb = ((const float4*)(x + rb))[tid];

    float v[4];
    v[0] = (bf2f((u16)(a0.x & 0xffff)) + bf2f((u16)(a1.x & 0xffff))) * inv + xb.x;
    v[1] = (bf2f((u16)(a0.x >> 16))    + bf2f((u16)(a1.x >> 16)))    * inv + xb.y;
    v[2] = (bf2f((u16)(a0.y & 0xffff)) + bf2f((u16)(a1.y & 0xffff))) * inv + xb.z;
    v[3] = (bf2f((u16)(a0.y >> 16))    + bf2f((u16)(a1.y >> 16)))    * inv + xb.w;

    float sm  = v[0] + v[1] + v[2] + v[3];
    float s2 = v[0]*v[0] + v[1]*v[1] + v[2]*v[2] + v[3]*v[3];
#pragma unroll
    for (int off = 1; off < 64; off <<= 1) {
        sm += __shfl_xor(sm, off, 64);
        s2 += __shfl_xor(s2, off, 64);
    }

    __shared__ float red[2][4];
    int wave = tid >> 6, lane = tid & 63;
    if (lane == 0) { red[0][wave] = sm; red[1][wave] = s2; }
    __syncthreads();
    float st  = red[0][0] + red[0][1] + red[0][2] + red[0][3];
    float s2t = red[1][0] + red[1][1] + red[1][2] + red[1][3];

    float mu   = st * (1.0f / D_MODEL);
    float var  = s2t * (1.0f / D_MODEL) - mu * mu;
    float rstd = rsqrtf(var + 1e-5f);

    float4 g  = ((const float4*)(gamma))[tid];
    float4 bt = ((const float4*)(beta))[tid];
    float4 o;
    o.x = (v[0] - mu) * rstd * g.x + bt.x;
    o.y = (v[1] - mu) * rstd * g.y + bt.y;
    o.z = (v[2] - mu) * rstd * g.z + bt.z;
    o.w = (v[3] - mu) * rstd * g.w + bt.w;
    ((float4*)(out + rb))[tid] = o;
}

// ---------------------------------------------------------------------------
extern "C" void kernel_launch(void* const* d_in, const int* in_sizes, int n_in,
                              void* d_out, int out_size, void* d_ws, size_t ws_size,
                              hipStream_t stream) {
    const float* x     = (const float*)d_in[0];
    const float* wq    = (const float*)d_in[1];
    const float* bq    = (const float*)d_in[2];
    const float* wk    = (const float*)d_in[3];
    const float* bk    = (const float*)d_in[4];
    const float* wv    = (const float*)d_in[5];
    const float* bv    = (const float*)d_in[6];
    const float* gamma = (const float*)d_in[7];
    const float* beta  = (const float*)d_in[8];
    float* outp = (float*)d_out;

    char* ws = (char*)d_ws;
    u16*   xb    = (u16*)(ws);                        //  8 MB
    u16*   wqb   = (u16*)(ws + ((size_t)8  << 20));   //  2 MB
    u16*   wkb   = (u16*)(ws + ((size_t)10 << 20));   //  2 MB
    u16*   wvb   = (u16*)(ws + ((size_t)12 << 20));   //  2 MB
    u16*   qb    = (u16*)(ws + ((size_t)16 << 20));   //  8 MB (swizzled)
    u16*   kb    = (u16*)(ws + ((size_t)24 << 20));   //  8 MB (swizzled)
    u16*   vt    = (u16*)(ws + ((size_t)32 << 20));   //  8 MB (transposed+swizzled)
    u16*   abp   = (u16*)(ws + ((size_t)40 << 20));   // 16 MB: 2 x bf16 partial O
    float* lsums = (float*)(ws + ((size_t)56 << 20)); // 512 KB row sums

    conv_all<<<dim3((NX4 + 3 * NW4) / 256), 256, 0, stream>>>(
        x, wq, wk, wv, xb, wqb, wkb, wvb);
    qkv_gemm<<<dim3(24 * 32), 256, 0, stream>>>(xb, wqb, bq, wkb, bk, wvb, bv, qb, kb, vt);
    attn_kernel<<<dim3(1024), 256, 0, stream>>>(qb, kb, vt, abp, lsums);
    add_ln<<<dim3(2 * SEQ), 256, 0, stream>>>(abp, lsums, x, gamma, beta, outp);
}

// Round 10
// 202.014 us; speedup vs baseline: 1.0080x; 1.0080x over previous
//
#include <hip/hip_runtime.h>

typedef unsigned short u16;
typedef unsigned int   u32;
typedef __bf16 bf16x8 __attribute__((ext_vector_type(8)));
typedef float  f32x4  __attribute__((ext_vector_type(4)));

#define D_MODEL 1024
#define SEQ     2048
#define NHEAD   16
#define HD      64
// (1/sqrt(64)) * log2(e): folded into Q at the projection epilogue
#define SOFTMAX_SCL 0.18033688011112042f

__device__ __forceinline__ u16 f2bf(float f) {
    u32 u;
    __builtin_memcpy(&u, &f, 4);
    u32 r = (u + 0x7fffu + ((u >> 16) & 1u)) >> 16;
    return (u16)r;
}
__device__ __forceinline__ float bf2f(u16 v) {
    u32 u = ((u32)v) << 16;
    float f;
    __builtin_memcpy(&f, &u, 4);
    return f;
}

__device__ __forceinline__ void async_copy16(const u16* g, u16* l) {
    __builtin_amdgcn_global_load_lds(
        (__attribute__((address_space(1))) void*)g,
        (__attribute__((address_space(3))) void*)l, 16, 0, 0);
}

// pack 4 fp32 -> 4 bf16 (RNE) as uint2
__device__ __forceinline__ uint2 pack4(float a, float b, float c, float d) {
    uint2 r;
    r.x = (u32)f2bf(a) | ((u32)f2bf(b) << 16);
    r.y = (u32)f2bf(c) | ((u32)f2bf(d) << 16);
    return r;
}

// ---------------------------------------------------------------------------
// fused fp32 -> bf16 conversion for x, wq, wk, wv (one launch)
// ---------------------------------------------------------------------------
#define NX4 ((2 * SEQ * D_MODEL) / 4)     // 1,048,576
#define NW4 ((D_MODEL * D_MODEL) / 4)     //   262,144
__global__ __launch_bounds__(256) void conv_all(
    const float* __restrict__ x,  const float* __restrict__ wq,
    const float* __restrict__ wk, const float* __restrict__ wv,
    u16* __restrict__ xb, u16* __restrict__ wqb,
    u16* __restrict__ wkb, u16* __restrict__ wvb)
{
    int i = blockIdx.x * 256 + threadIdx.x;
    const float* src; u16* dst; int off;
    if (i < NX4)            { src = x;  dst = xb;  off = i; }
    else if (i < NX4 + NW4) { src = wq; dst = wqb; off = i - NX4; }
    else if (i < NX4 + 2 * NW4) { src = wk; dst = wkb; off = i - NX4 - NW4; }
    else                    { src = wv; dst = wvb; off = i - NX4 - 2 * NW4; }
    float4 a = ((const float4*)src)[off];
    ushort4 o;
    o.x = f2bf(a.x); o.y = f2bf(a.y); o.z = f2bf(a.z); o.w = f2bf(a.w);
    ((ushort4*)dst)[off] = o;
}

// ---------------------------------------------------------------------------
// QKV projection, 128x128 tile, BK=64, global_load_lds, XOR-swizzled LDS.
// 1-D XCD-pinned grid: bid = (z*8+bx) + 24*by -> bid%8 constant across by.
// OPERAND ORDER per z puts the output-contiguous dim in the MFMA m-direction
// (each thread holds 4 consecutive m-rows) -> epilogue = 16x dwordx2 stores:
//   z<2 (Q,K): A=W, B=X -> D[feat][token]; out[token][feat-swizzled]
//   z=2 (V):   A=X, B=W -> D[token][feat]; vt[b][h][d][s-swizzled]
// ---------------------------------------------------------------------------
__global__ __launch_bounds__(256) void qkv_gemm(
    const u16* __restrict__ xb,
    const u16* __restrict__ wqb, const float* __restrict__ bq,
    const u16* __restrict__ wkb, const float* __restrict__ bk,
    const u16* __restrict__ wvb, const float* __restrict__ bv,
    u16* __restrict__ qb, u16* __restrict__ kb, u16* __restrict__ vt)
{
    const int bid  = blockIdx.x;
    const int pair = bid % 24;
    const int by   = bid / 24;          // token-block 0..31
    const int z    = pair >> 3;
    const int bx   = pair & 7;          // feature-block 0..7

    const u16* Ap; const u16* Bp;
    int m0, n0;
    if (z < 2) {
        Ap = (z == 1) ? wkb : wqb;  Bp = xb;
        m0 = bx * 128;              // feat (m)
        n0 = by * 128;              // token (n)
    } else {
        Ap = xb;  Bp = wvb;
        m0 = by * 128;              // token (m)
        n0 = bx * 128;              // feat (n)
    }

    __shared__ u16 As[128 * 64];
    __shared__ u16 Bs[128 * 64];

    const int tid  = threadIdx.x;
    const int wave = tid >> 6;
    const int lane = tid & 63;
    const int quad = lane >> 4;
    const int l16  = lane & 15;
    const int wm   = wave >> 1;
    const int wn   = wave & 1;
    const int swz  = l16 & 7;

    int rr[4], co[4];
#pragma unroll
    for (int t = 0; t < 4; ++t) {
        int ch = (wave * 4 + t) * 64 + lane;
        rr[t] = ch >> 3;
        co[t] = ((ch & 7) ^ (rr[t] & 7)) * 8;
    }

    f32x4 acc[4][4] = {};

    for (int kt = 0; kt < D_MODEL; kt += 64) {
        __syncthreads();
#pragma unroll
        for (int t = 0; t < 4; ++t) {
            int chbase = (wave * 4 + t) * 64;
            async_copy16(Ap + (size_t)(m0 + rr[t]) * D_MODEL + kt + co[t], As + chbase * 8);
            async_copy16(Bp + (size_t)(n0 + rr[t]) * D_MODEL + kt + co[t], Bs + chbase * 8);
        }
        __syncthreads();

#pragma unroll
        for (int kc = 0; kc < 2; ++kc) {
            bf16x8 af[4], bf_[4];
#pragma unroll
            for (int i = 0; i < 4; ++i)
                af[i] = *(const bf16x8*)&As[(wm * 64 + i * 16 + l16) * 64 + (((kc * 4 + quad) ^ swz) << 3)];
#pragma unroll
            for (int j = 0; j < 4; ++j)
                bf_[j] = *(const bf16x8*)&Bs[(wn * 64 + j * 16 + l16) * 64 + (((kc * 4 + quad) ^ swz) << 3)];
#pragma unroll
            for (int i = 0; i < 4; ++i)
#pragma unroll
                for (int j = 0; j < 4; ++j)
                    acc[i][j] = __builtin_amdgcn_mfma_f32_16x16x32_bf16(af[i], bf_[j], acc[i][j], 0, 0, 0);
        }
    }

    const int chunk_lo = (quad & 1) * 4;       // within-chunk offset (u16)
    if (z < 2) {
        u16* out = (z == 1) ? kb : qb;
        const float* bi = (z == 1) ? bk : bq;
        const float scl = (z == 1) ? 1.0f : SOFTMAX_SCL;
        const int fblk = m0 + wm * 64;         // 64-aligned feature block
#pragma unroll
        for (int i = 0; i < 4; ++i) {
            const int fb = fblk + i * 16 + quad * 4;   // 4 consecutive feats
            float4 b4 = *(const float4*)&bi[fb];
            const int chunk = i * 2 + (quad >> 1);     // (feat>>3)&7
#pragma unroll
            for (int j = 0; j < 4; ++j) {
                int token = n0 + wn * 64 + j * 16 + l16;
                uint2 pk = pack4((acc[i][j][0] + b4.x) * scl,
                                 (acc[i][j][1] + b4.y) * scl,
                                 (acc[i][j][2] + b4.z) * scl,
                                 (acc[i][j][3] + b4.w) * scl);
                size_t addr = (size_t)token * D_MODEL + fblk
                            + ((chunk ^ (token & 7)) << 3) + chunk_lo;
                *(uint2*)&out[addr] = pk;
            }
        }
    } else {
        // m = token (4 consecutive), n = feat
#pragma unroll
        for (int j = 0; j < 4; ++j) {
            int feat = n0 + wn * 64 + j * 16 + l16;
            float bias = bv[feat];
            int hh = feat >> 6, d = feat & 63;
            const size_t rowbase = ((size_t)hh * HD + d) * SEQ;  // b added below
#pragma unroll
            for (int i = 0; i < 4; ++i) {
                int tok = m0 + wm * 64 + i * 16 + quad * 4;      // 4 consecutive
                int b = tok >> 11, s = tok & 2047;
                const int chunk = i * 2 + (quad >> 1);           // (s>>3)&7
                uint2 pk = pack4(acc[i][j][0] + bias, acc[i][j][1] + bias,
                                 acc[i][j][2] + bias, acc[i][j][3] + bias);
                size_t addr = (size_t)b * NHEAD * HD * SEQ + rowbase
                            + (s & ~63) + ((chunk ^ (d & 7)) << 3) + chunk_lo;
                *(uint2*)&vt[addr] = pk;
            }
        }
    }
}

// ---------------------------------------------------------------------------
// Attention (round-8 proven structure): Q-tile 128/block, 2-way key split,
// XCD-pinned grid, single-buffer async staging, no-max softmax with
// deferred row sums; writes unnormalized O (bf16) + row sums.
// ---------------------------------------------------------------------------
__global__ __launch_bounds__(256) void attn_kernel(
    const u16* __restrict__ qb, const u16* __restrict__ kb, const u16* __restrict__ vtg,
    u16* __restrict__ abp, float* __restrict__ lsums)
{
    const int bid  = blockIdx.x;
    const int bh   = bid & 31;
    const int b    = bh >> 4;
    const int h    = bh & 15;
    const int q0   = ((bid >> 5) & 15) * 128;
    const int half = bid >> 9;

    const int tid  = threadIdx.x;
    const int wave = tid >> 6;
    const int lane = tid & 63;
    const int quad = lane >> 4;
    const int l16  = lane & 15;
    const int swz  = l16 & 7;

    __shared__ u16 Ks[4096];          // [token][chunk^(token&7)][8]
    __shared__ u16 Vt[4096];          // [d][chunk^(d&7)][8]
    __shared__ u16 Ps[8 * 1024];      // [wave][rb][r][nb][lane]

    const size_t kbase = (size_t)b * SEQ * D_MODEL + h * 64;
    const size_t vbase = (size_t)(b * NHEAD + h) * HD * SEQ;

    // Q fragments direct from swizzled global: 2 row groups x 2 k-chunks
    bf16x8 aq[2][2];
#pragma unroll
    for (int rb = 0; rb < 2; ++rb) {
        const int qrow = q0 + wave * 32 + rb * 16 + l16;
        const u16* qrp = qb + (size_t)qrow * D_MODEL + h * 64;
        aq[rb][0] = *(const bf16x8*)(qrp + ((quad ^ swz) << 3));
        aq[rb][1] = *(const bf16x8*)(qrp + (((4 + quad) ^ swz) << 3));
    }

    // staging pointers (offset into this block's 1024-key half)
    const int r0 = tid >> 3, r1 = (tid + 256) >> 3;
    const int cs8 = (tid & 7) * 8;
    const u16* kg0 = kb + kbase + (size_t)(half * 1024 + r0) * D_MODEL + cs8;
    const u16* kg1 = kb + kbase + (size_t)(half * 1024 + r1) * D_MODEL + cs8;
    const u16* vg0 = vtg + vbase + (size_t)r0 * SEQ + half * 1024 + cs8;
    const u16* vg1 = vtg + vbase + (size_t)r1 * SEQ + half * 1024 + cs8;
    const int wofs = wave * 512;

    f32x4 oacc[2][4] = {};
    float lsum[2][4] = {};

    for (int t = 0; t < 16; ++t) {
        __syncthreads();   // previous tile fully consumed
        async_copy16(kg0, Ks + wofs);
        async_copy16(kg1, Ks + 2048 + wofs);
        async_copy16(vg0, Vt + wofs);
        async_copy16(vg1, Vt + 2048 + wofs);
        kg0 += 64 * D_MODEL; kg1 += 64 * D_MODEL;
        vg0 += 64;           vg1 += 64;
        __syncthreads();   // staging complete (vmcnt drained at barrier)

        // S = Q K^T  (Q pre-scaled: S already in log2 units)
        f32x4 sacc[2][4] = {};
#pragma unroll
        for (int c = 0; c < 2; ++c) {
            bf16x8 bk_[4];
#pragma unroll
            for (int nb = 0; nb < 4; ++nb)
                bk_[nb] = *(const bf16x8*)&Ks[(nb * 16 + l16) * 64 + (((c * 4 + quad) ^ swz) << 3)];
#pragma unroll
            for (int rb = 0; rb < 2; ++rb)
#pragma unroll
                for (int nb = 0; nb < 4; ++nb)
                    sacc[rb][nb] = __builtin_amdgcn_mfma_f32_16x16x32_bf16(aq[rb][c], bk_[nb], sacc[rb][nb], 0, 0, 0);
        }

        // p = 2^S; lane-local partial sums; P -> Ps (trunc to bf16)
#pragma unroll
        for (int rb = 0; rb < 2; ++rb)
#pragma unroll
            for (int r = 0; r < 4; ++r)
#pragma unroll
                for (int nb = 0; nb < 4; ++nb) {
                    float e = exp2f(sacc[rb][nb][r]);
                    lsum[rb][r] += e;
                    u32 bits;
                    __builtin_memcpy(&bits, &e, 4);
                    Ps[wave * 2048 + rb * 1024 + r * 256 + nb * 64 + lane] = (u16)(bits >> 16);
                }

        // O += P V   (Ps wave-private: wave-local DS ordering, no barrier)
#pragma unroll
        for (int c = 0; c < 2; ++c) {
            bf16x8 ap[2];
#pragma unroll
            for (int rb = 0; rb < 2; ++rb)
                ap[rb] = *(const bf16x8*)&Ps[wave * 2048 + rb * 1024 + (l16 & 3) * 256
                                             + (c * 2 + (quad >> 1)) * 64
                                             + (l16 >> 2) * 16 + (quad & 1) * 8];
            bf16x8 bv_[4];
#pragma unroll
            for (int nb = 0; nb < 4; ++nb)
                bv_[nb] = *(const bf16x8*)&Vt[(nb * 16 + l16) * 64 + (((c * 4 + quad) ^ swz) << 3)];
#pragma unroll
            for (int rb = 0; rb < 2; ++rb)
#pragma unroll
                for (int nb = 0; nb < 4; ++nb)
                    oacc[rb][nb] = __builtin_amdgcn_mfma_f32_16x16x32_bf16(ap[rb], bv_[nb], oacc[rb][nb], 0, 0, 0);
        }
    }

    // epilogue: row sums + UNNORMALIZED partial O (bf16) to ws
#pragma unroll
    for (int rb = 0; rb < 2; ++rb)
#pragma unroll
        for (int r = 0; r < 4; ++r) {
            float s = lsum[rb][r];
            s += __shfl_xor(s, 1, 64);
            s += __shfl_xor(s, 2, 64);
            s += __shfl_xor(s, 4, 64);
            s += __shfl_xor(s, 8, 64);
            int row = q0 + wave * 32 + rb * 16 + quad * 4 + r;
            if (l16 == 0)
                lsums[((size_t)bh * 2 + half) * SEQ + row] = s;
#pragma unroll
            for (int nb = 0; nb < 4; ++nb) {
                int d = nb * 16 + l16;
                abp[(size_t)half * SEQ * 2 * D_MODEL
                    + ((size_t)b * SEQ + row) * D_MODEL + h * 64 + d] = f2bf(oacc[rb][nb][r]);
            }
        }
}

// ---------------------------------------------------------------------------
// combine key-halves + residual add + LayerNorm, one block per row of 1024
// ---------------------------------------------------------------------------
__global__ __launch_bounds__(256) void add_ln(
    const u16* __restrict__ abp, const float* __restrict__ lsums,
    const float* __restrict__ x,
    const float* __restrict__ gamma, const float* __restrict__ beta,
    float* __restrict__ out)
{
    const int row = blockIdx.x;           // (b, s)
    const int tid = threadIdx.x;
    const size_t rb = (size_t)row * D_MODEL;
    const int b = row >> 11, s = row & 2047;
    const int h = tid >> 4;               // head of this thread's 4 columns
    const int bh = b * NHEAD + h;

    float l = lsums[(size_t)bh * 2 * SEQ + s] + lsums[((size_t)bh * 2 + 1) * SEQ + s];
    float inv = 1.0f / l;

    uint2 a0 = ((const uint2*)(abp + rb))[tid];
    uint2 a1 = ((const uint2*)(abp + (size_t)SEQ * 2 * D_MODEL + rb))[tid];
    float4 xb = ((const float4*)(x + rb))[tid];

    float v[4];
    v[0] = (bf2f((u16)(a0.x & 0xffff)) + bf2f((u16)(a1.x & 0xffff))) * inv + xb.x;
    v[1] = (bf2f((u16)(a0.x >> 16))    + bf2f((u16)(a1.x >> 16)))    * inv + xb.y;
    v[2] = (bf2f((u16)(a0.y & 0xffff)) + bf2f((u16)(a1.y & 0xffff))) * inv + xb.z;
    v[3] = (bf2f((u16)(a0.y >> 16))    + bf2f((u16)(a1.y >> 16)))    * inv + xb.w;

    float sm  = v[0] + v[1] + v[2] + v[3];
    float s2 = v[0]*v[0] + v[1]*v[1] + v[2]*v[2] + v[3]*v[3];
#pragma unroll
    for (int off = 1; off < 64; off <<= 1) {
        sm += __shfl_xor(sm, off, 64);
        s2 += __shfl_xor(s2, off, 64);
    }

    __shared__ float red[2][4];
    int wave = tid >> 6, lane = tid & 63;
    if (lane == 0) { red[0][wave] = sm; red[1][wave] = s2; }
    __syncthreads();
    float st  = red[0][0] + red[0][1] + red[0][2] + red[0][3];
    float s2t = red[1][0] + red[1][1] + red[1][2] + red[1][3];

    float mu   = st * (1.0f / D_MODEL);
    float var  = s2t * (1.0f / D_MODEL) - mu * mu;
    float rstd = rsqrtf(var + 1e-5f);

    float4 g  = ((const float4*)(gamma))[tid];
    float4 bt = ((const float4*)(beta))[tid];
    float4 o;
    o.x = (v[0] - mu) * rstd * g.x + bt.x;
    o.y = (v[1] - mu) * rstd * g.y + bt.y;
    o.z = (v[2] - mu) * rstd * g.z + bt.z;
    o.w = (v[3] - mu) * rstd * g.w + bt.w;
    ((float4*)(out + rb))[tid] = o;
}

// ---------------------------------------------------------------------------
extern "C" void kernel_launch(void* const* d_in, const int* in_sizes, int n_in,
                              void* d_out, int out_size, void* d_ws, size_t ws_size,
                              hipStream_t stream) {
    const float* x     = (const float*)d_in[0];
    const float* wq    = (const float*)d_in[1];
    const float* bq    = (const float*)d_in[2];
    const float* wk    = (const float*)d_in[3];
    const float* bk    = (const float*)d_in[4];
    const float* wv    = (const float*)d_in[5];
    const float* bv    = (const float*)d_in[6];
    const float* gamma = (const float*)d_in[7];
    const float* beta  = (const float*)d_in[8];
    float* outp = (float*)d_out;

    char* ws = (char*)d_ws;
    u16*   xb    = (u16*)(ws);                        //  8 MB
    u16*   wqb   = (u16*)(ws + ((size_t)8  << 20));   //  2 MB
    u16*   wkb   = (u16*)(ws + ((size_t)10 << 20));   //  2 MB
    u16*   wvb   = (u16*)(ws + ((size_t)12 << 20));   //  2 MB
    u16*   qb    = (u16*)(ws + ((size_t)16 << 20));   //  8 MB (swizzled)
    u16*   kb    = (u16*)(ws + ((size_t)24 << 20));   //  8 MB (swizzled)
    u16*   vt    = (u16*)(ws + ((size_t)32 << 20));   //  8 MB (transposed+swizzled)
    u16*   abp   = (u16*)(ws + ((size_t)40 << 20));   // 16 MB: 2 x bf16 partial O
    float* lsums = (float*)(ws + ((size_t)56 << 20)); // 512 KB row sums

    conv_all<<<dim3((NX4 + 3 * NW4) / 256), 256, 0, stream>>>(
        x, wq, wk, wv, xb, wqb, wkb, wvb);
    qkv_gemm<<<dim3(24 * 32), 256, 0, stream>>>(xb, wqb, bq, wkb, bk, wvb, bv, qb, kb, vt);
    attn_kernel<<<dim3(1024), 256, 0, stream>>>(qb, kb, vt, abp, lsums);
    add_ln<<<dim3(2 * SEQ), 256, 0, stream>>>(abp, lsums, x, gamma, beta, outp);
}